// Round 20
// baseline (235.216 us; speedup 1.0000x reference)
//
#include <hip/hip_runtime.h>
#include <math.h>

// Problem constants (fixed by reference)
#define MUL0    32
#define MUL1    16
#define RBFD    16
#define HIDD    64
#define WNUMEL  2304
#define FDIM    80
#define CPATH   0.14433756729740643f   // 1/sqrt(48)
#define C110    0.57735026918962576f   // 1/sqrt(3)

#define TE       128      // edges per block (8 waves x 16 edges)
#define NTHREADS 512
#define NITER    48       // column-tile iterations (divisible by 3)

#define W3N_ELEMS (NITER*6*512)    // 147456 u16 (consumption-ordered, CPATH-folded)
#define W1B_ELEMS (4*64*8)         // 2048
#define W2B_ELEMS (4*2*64*8)       // 4096

// k_edge LDS byte map (37,376 B)
#define FS4_U16  0
#define XS_U16   2048
#define XV_U16   6144
#define SH_B     24576             // f32[128][4] -> 26624
#define SRC_B    26624             // int[128]    -> 27136
#define DST_B    27136             // int[128]    -> 27648
#define B3_B     27648             // f32[2304] (reordered, CPATH-folded) -> 36864
#define EID_B    36864             // int[128]    -> 37376
#define SMEM_B   37376

typedef float          f32x4   __attribute__((ext_vector_type(4)));
typedef short          short8  __attribute__((ext_vector_type(8)));
typedef short          short4v __attribute__((ext_vector_type(4)));
typedef unsigned short u16;

__device__ __forceinline__ float silu(float v) {
    return v / (1.0f + __expf(-v));
}
__device__ __forceinline__ u16 f2bf(float f) {      // RNE fp32->bf16
    unsigned int u = __float_as_uint(f);
    u += 0x7fffu + ((u >> 16) & 1u);
    return (u16)(u >> 16);
}
__device__ __forceinline__ float bf2f(u16 s) {
    return __uint_as_float(((unsigned int)s) << 16);
}
__device__ __forceinline__ f32x4 cvt4(short4v s) {
    f32x4 r;
    r[0] = bf2f((u16)s[0]); r[1] = bf2f((u16)s[1]);
    r[2] = bf2f((u16)s[2]); r[3] = bf2f((u16)s[3]);
    return r;
}
__device__ __forceinline__ f32x4 mfma16(short8 a, short8 b, f32x4 c) {
    return __builtin_amdgcn_mfma_f32_16x16x32_bf16(a, b, c, 0, 0, 0);
}

// iteration t, pair p (0,1 -> 32-col halves; 2 -> 16-col tile) -> column tile
__device__ __forceinline__ int tile_of(int t, int pair) {
    if (t < 32) return (pair == 0) ? 2*t : (pair == 1) ? 2*t + 1 : 64 + t;
    int tt = t - 32;
    return (pair == 0) ? 112 + 2*tt : (pair == 1) ? 113 + 2*tt : 96 + tt;
}

// ---------------------------------------------------------------------------
// Kernel 0: pack w3 (x CPATH) into consumption-ordered bf16 fragments + w1b/w2b.
// ---------------------------------------------------------------------------
__global__ void k_prep(const float* __restrict__ w3,
                       const float* __restrict__ w1,
                       const float* __restrict__ w2,
                       u16* __restrict__ w3n,
                       u16* __restrict__ w1b,
                       u16* __restrict__ w2b) {
    int idx = blockIdx.x * 256 + threadIdx.x;
    if (idx < W3N_ELEMS) {
        int j = idx & 7, l = (idx >> 3) & 63, f = idx >> 9;
        int t = f / 6, s = f - 6 * t, pair = s >> 1, kh = s & 1;
        int tile = tile_of(t, pair);
        int k = kh * 32 + 8 * (l >> 4) + j;
        int c = tile * 16 + (l & 15);
        w3n[idx] = f2bf(CPATH * w3[k * WNUMEL + c]);
        return;
    }
    idx -= W3N_ELEMS;
    if (idx < W1B_ELEMS) {
        int j = idx & 7, l = (idx >> 3) & 63, ct = idx >> 9;
        int k = 8 * (l >> 4) + j;
        int c = ct * 16 + (l & 15);
        w1b[idx] = (k < RBFD) ? f2bf(w1[k * HIDD + c]) : (u16)0;
        return;
    }
    idx -= W1B_ELEMS;
    if (idx < W2B_ELEMS) {
        int j = idx & 7, l = (idx >> 3) & 63, kh = (idx >> 9) & 1, ct = idx >> 10;
        int k = kh * 32 + 8 * (l >> 4) + j;
        int c = ct * 16 + (l & 15);
        w2b[idx] = f2bf(w2[k * HIDD + c]);
    }
}

// ---------------------------------------------------------------------------
// CSR build: count -> PARALLEL hierarchical scan -> fill
// ---------------------------------------------------------------------------
__global__ void k_cnt(const int* __restrict__ edst, int* __restrict__ cnt, int E) {
    int e = blockIdx.x * 256 + threadIdx.x;
    if (e < E) atomicAdd(&cnt[edst[e]], 1);
}

// per-block reduction: bsum[b] = sum of cnt[b*256 .. b*256+255]
__global__ __launch_bounds__(256)
void k_scan_part(const int* __restrict__ cnt, int* __restrict__ bsum, int N) {
    __shared__ int sh[256];
    int i = blockIdx.x * 256 + threadIdx.x;
    sh[threadIdx.x] = (i < N) ? cnt[i] : 0;
    __syncthreads();
    for (int off = 128; off > 0; off >>= 1) {
        if (threadIdx.x < off) sh[threadIdx.x] += sh[threadIdx.x + off];
        __syncthreads();
    }
    if (threadIdx.x == 0) bsum[blockIdx.x] = sh[0];
}

// single small block: exclusive scan of nb (<=256) block sums, in place
__global__ __launch_bounds__(256)
void k_scan_top(int* __restrict__ bsum, int nb) {
    __shared__ int sh[256];
    const int t = threadIdx.x;
    int orig = (t < nb) ? bsum[t] : 0;
    sh[t] = orig;
    __syncthreads();
    for (int off = 1; off < 256; off <<= 1) {
        int v = (t >= off) ? sh[t - off] : 0;
        __syncthreads();
        sh[t] += v;
        __syncthreads();
    }
    if (t < nb) bsum[t] = sh[t] - orig;   // exclusive
}

// per-block exclusive scan + block offset -> base
__global__ __launch_bounds__(256)
void k_scan_base(const int* __restrict__ cnt, const int* __restrict__ bsum,
                 int* __restrict__ base, int N) {
    __shared__ int sh[256];
    const int t = threadIdx.x;
    int i = blockIdx.x * 256 + t;
    int orig = (i < N) ? cnt[i] : 0;
    sh[t] = orig;
    __syncthreads();
    for (int off = 1; off < 256; off <<= 1) {
        int v = (t >= off) ? sh[t - off] : 0;
        __syncthreads();
        sh[t] += v;
        __syncthreads();
    }
    if (i < N) base[i] = bsum[blockIdx.x] + sh[t] - orig;
}

__global__ void k_fill(const int* __restrict__ edst,
                       const int* __restrict__ base,
                       int* __restrict__ cursor,
                       int* __restrict__ eidx, int E) {
    int e = blockIdx.x * 256 + threadIdx.x;
    if (e < E) {
        int d = edst[e];
        int p = atomicAdd(&cursor[d], 1);
        eidx[base[d] + p] = e;
    }
}

// one column-tile iteration's compute for this wave's single 16-edge row-tile
// (T5: setprio(1) keeps the MFMA cluster fed while sibling waves issue loads)
#define COMPUTE(T, BP) do {                                                    \
    float bs0 = s_b3[(T)*48 + lo];                                             \
    float bs1 = s_b3[(T)*48 + 16 + lo];                                        \
    float bs2 = s_b3[(T)*48 + 32 + lo];                                        \
    __builtin_amdgcn_s_setprio(1);                                             \
    f32x4 tA = {bs0,bs0,bs0,bs0};                                              \
    tA = mfma16(a0, BP[0], tA); tA = mfma16(a1, BP[1], tA);                    \
    f32x4 tB = {bs1,bs1,bs1,bs1};                                              \
    tB = mfma16(a0, BP[2], tB); tB = mfma16(a1, BP[3], tB);                    \
    f32x4 tC = {bs2,bs2,bs2,bs2};                                              \
    tC = mfma16(a0, BP[4], tC); tC = mfma16(a1, BP[5], tC);                    \
    __builtin_amdgcn_s_setprio(0);                                             \
    if ((T) < 32) {                                                            \
        f32x4 fx = cvt4(*(const short4v*)&S[XS_U16 + w*512 + (T)*16 + 4*g]);   \
        f32x4 f1 = fx * sh0v;                                                  \
        acc[0] += f1 * tA;                                                     \
        acc[1] += f1 * tB;                                                     \
        acc[2] += fx * tC;                                                     \
    } else {                                                                   \
        const int i_ = (T) - 32;                                               \
        f32x4 f4 = cvt4(*(const short4v*)&S[FS4_U16 + w*256 + i_*16 + 4*g]);   \
        acc[0] += f4 * tA;                                                     \
        acc[1] += f4 * tB;                                                     \
        acc[3] += cvt4(*(const short4v*)&S[XV_U16 + w*768 + (0 +i_)*16 + 4*g]) * tC; \
        acc[4] += cvt4(*(const short4v*)&S[XV_U16 + w*768 + (16+i_)*16 + 4*g]) * tC; \
        acc[5] += cvt4(*(const short4v*)&S[XV_U16 + w*768 + (32+i_)*16 + 4*g]) * tC; \
    }                                                                          \
} while (0)

// ---------------------------------------------------------------------------
// Kernel 1: MFMA MLP + fused W-tile contraction + run-combined atomic scatter.
// Champion structure: 8 waves x 16 edges, depth-3 register pipeline (VGPR=64),
// dst-sorted (CSR) edge order, free-running main loop + setprio on MFMA.
// ---------------------------------------------------------------------------
__global__ __launch_bounds__(NTHREADS, 4)
void k_edge(const float* __restrict__ x,
            const int*   __restrict__ esrc,
            const int*   __restrict__ edst,
            const float* __restrict__ esh,
            const float* __restrict__ erbf,
            const int*   __restrict__ eidx,
            const u16*   __restrict__ w1b,
            const float* __restrict__ b1,
            const u16*   __restrict__ w2b,
            const float* __restrict__ b2,
            const u16*   __restrict__ w3n,
            const float* __restrict__ b3,
            float* __restrict__ agg,
            int E)
{
    __shared__ alignas(16) unsigned char smem[SMEM_B];
    u16*   S     = (u16*)smem;            // features; MLP-phase alias s_hb[128][72]
    float* s_sh  = (float*)(smem + SH_B);
    int*   s_src = (int*)(smem + SRC_B);
    int*   s_dst = (int*)(smem + DST_B);
    float* s_b3  = (float*)(smem + B3_B);
    int*   s_eid = (int*)(smem + EID_B);

    const int tid = threadIdx.x;
    const int eb  = blockIdx.x * TE;
    const int w   = tid >> 6;        // wave 0..7, owns edges 16w..16w+15
    const int l   = tid & 63;
    const int lo  = l & 15;
    const int g   = l >> 4;

    // ---- stage edge metadata in CSR order (guarded; last block partial) ----
    if (tid < TE) {
        int eg  = eb + tid;
        int eid = (eg < E) ? eidx[eg] : 0;
        s_eid[tid] = eid;
        s_src[tid] = esrc[eid];
        s_dst[tid] = (eg < E) ? edst[eid] : 0;
        f32x4 sh4 = {0.f, 0.f, 0.f, 0.f};
        if (eg < E) sh4 = *(const f32x4*)(esh + (size_t)eid * 4);
        *(f32x4*)&s_sh[tid * 4] = sh4;     // sh=0 zeroes pad-edge output
    }
    __syncthreads();

    // ---- MLP (MFMA): rbf -> h1 -> h (bf16 rows, stride 72, wave-private) ----
    float cb1[4], cb2[4];
    #pragma unroll
    for (int ct = 0; ct < 4; ++ct) { cb1[ct] = b1[ct*16 + lo]; cb2[ct] = b2[ct*16 + lo]; }
    const short8* W1B = (const short8*)w1b;
    const short8* W2B = (const short8*)w2b;
    const int e0 = 16 * w;

    {
        short8 ar = {0,0,0,0,0,0,0,0};
        if (g < 2 && (eb + e0 + lo) < E) {
            const float* rp = erbf + (size_t)s_eid[e0 + lo] * RBFD + 8 * g;
            f32x4 r0 = *(const f32x4*)rp;
            f32x4 r1 = *(const f32x4*)(rp + 4);
            ar[0]=f2bf(r0[0]); ar[1]=f2bf(r0[1]); ar[2]=f2bf(r0[2]); ar[3]=f2bf(r0[3]);
            ar[4]=f2bf(r1[0]); ar[5]=f2bf(r1[1]); ar[6]=f2bf(r1[2]); ar[7]=f2bf(r1[3]);
        }
        #pragma unroll
        for (int ct = 0; ct < 4; ++ct) {
            f32x4 t = {cb1[ct], cb1[ct], cb1[ct], cb1[ct]};
            t = mfma16(ar, W1B[ct * 64 + l], t);
            #pragma unroll
            for (int r = 0; r < 4; ++r)
                S[(e0 + 4*g + r) * 72 + ct*16 + lo] = f2bf(silu(t[r]));
        }
    }
    {
        short8 h0 = *(const short8*)&S[(e0 + lo) * 72 + 0  + 8*g];
        short8 h1 = *(const short8*)&S[(e0 + lo) * 72 + 32 + 8*g];
        #pragma unroll
        for (int ct = 0; ct < 4; ++ct) {
            f32x4 t = {cb2[ct], cb2[ct], cb2[ct], cb2[ct]};
            t = mfma16(h0, W2B[(ct*2 + 0) * 64 + l], t);
            t = mfma16(h1, W2B[(ct*2 + 1) * 64 + l], t);
            #pragma unroll
            for (int r = 0; r < 4; ++r)
                S[(e0 + 4*g + r) * 72 + ct*16 + lo] = f2bf(silu(t[r]));
        }
    }
    // A-fragments for the main loop (this wave's single row-tile)
    short8 a0 = *(const short8*)&S[(e0 + lo) * 72 + 0  + 8*g];
    short8 a1 = *(const short8*)&S[(e0 + lo) * 72 + 32 + 8*g];
    __syncthreads();   // h rows dead; feature region may overwrite

    // ---- features (bf16) + reordered CPATH-folded b3 staging ----
    if (tid < TE) {
        const int el = tid, grp = el >> 4, e16 = el & 15;
        const float sh0 = s_sh[el*4 + 0];
        const float sh1 = s_sh[el*4 + 1];
        const float sh2 = s_sh[el*4 + 2];
        const float sh3 = s_sh[el*4 + 3];
        const float* xrow = x + (size_t)s_src[el] * FDIM;
        u16* fs4B = S + FS4_U16 + grp * 256 + e16;   // W4 path (C110 * xv.shv)
        u16* xsB  = S + XS_U16  + grp * 512 + e16;   // raw xs (sh_s folded at use)
        u16* xvB  = S + XV_U16  + grp * 768 + e16;   // xv * sh_s
        #pragma unroll
        for (int v = 0; v < 8; ++v) {
            f32x4 x4 = *(const f32x4*)(xrow + 4 * v);
            #pragma unroll
            for (int c2 = 0; c2 < 4; ++c2)
                xsB[(4 * v + c2) * 16] = f2bf(x4[c2]);
        }
        float buf[48];
        #pragma unroll
        for (int v = 0; v < 12; ++v) {
            f32x4 t4 = *(const f32x4*)(xrow + MUL0 + 4 * v);
            buf[4*v]=t4[0]; buf[4*v+1]=t4[1]; buf[4*v+2]=t4[2]; buf[4*v+3]=t4[3];
        }
        #pragma unroll
        for (int i = 0; i < 16; ++i) {
            float v0 = buf[3*i], v1 = buf[3*i+1], v2 = buf[3*i+2];
            xvB[(0  + i) * 16] = f2bf(v0 * sh0);
            xvB[(16 + i) * 16] = f2bf(v1 * sh0);
            xvB[(32 + i) * 16] = f2bf(v2 * sh0);
            fs4B[i * 16]       = f2bf(C110 * (v0*sh1 + v1*sh2 + v2*sh3));
        }
    } else {
        for (int idx = tid - TE; idx < WNUMEL; idx += NTHREADS - TE) {
            int t = idx / 48, r = idx - 48 * t, pair = r >> 4, lo16 = r & 15;
            s_b3[idx] = CPATH * b3[tile_of(t, pair) * 16 + lo16];
        }
    }
    __syncthreads();

    // per-thread sh_s broadcast for the W1-path fold (4 edges per lane-group)
    f32x4 sh0v;
    #pragma unroll
    for (int r = 0; r < 4; ++r)
        sh0v[r] = s_sh[(16*w + 4*g + r) * 4];

    // ---- main loop: DEPTH-3 register pipeline, uniform distance, free-run ----
    const short8* WB = (const short8*)w3n;
    f32x4 acc[6];
    #pragma unroll
    for (int p = 0; p < 6; ++p) acc[p] = (f32x4){0.f,0.f,0.f,0.f};

    short8 p0[6], p1[6], p2[6];
    #pragma unroll
    for (int s = 0; s < 6; ++s) {
        p0[s] = WB[0*384 + s*64 + l];
        p1[s] = WB[1*384 + s*64 + l];
        p2[s] = WB[2*384 + s*64 + l];
    }

    for (int t = 0; t < NITER; t += 3) {
        COMPUTE(t, p0);
        {   const int tn = (t + 3 < NITER) ? (t + 3) : 0;   // wrap: result unused
            #pragma unroll
            for (int s = 0; s < 6; ++s) p0[s] = WB[tn*384 + s*64 + l];
        }
        COMPUTE(t + 1, p1);
        {   const int tn = (t + 4 < NITER) ? (t + 4) : 0;
            #pragma unroll
            for (int s = 0; s < 6; ++s) p1[s] = WB[tn*384 + s*64 + l];
        }
        COMPUTE(t + 2, p2);
        {   const int tn = (t + 5 < NITER) ? (t + 5) : 0;
            #pragma unroll
            for (int s = 0; s < 6; ++s) p2[s] = WB[tn*384 + s*64 + l];
        }
    }

    // ---- epilogue: run-combined atomic scatter (CSR order -> equal dst runs)
    int   dl[4];
    float o0[4], o1[4], o2[4], o3[4], o4[4];
    #pragma unroll
    for (int r = 0; r < 4; ++r) {
        const int e_loc = 16*w + 4*g + r;
        dl[r] = s_dst[e_loc];
        float sv0 = s_sh[e_loc*4 + 1];
        float sv1 = s_sh[e_loc*4 + 2];
        float sv2 = s_sh[e_loc*4 + 3];
        o0[r] = acc[0][r];
        o1[r] = acc[1][r];
        o2[r] = sv0*acc[2][r] + acc[3][r];
        o3[r] = sv1*acc[2][r] + acc[4][r];
        o4[r] = sv2*acc[2][r] + acc[5][r];
    }
    float c0 = 0.f, c1 = 0.f, c2 = 0.f, c3 = 0.f, c4 = 0.f;
    #pragma unroll
    for (int r = 0; r < 4; ++r) {
        c0 += o0[r]; c1 += o1[r]; c2 += o2[r]; c3 += o3[r]; c4 += o4[r];
        bool flush = (r == 3) || (dl[r + 1] != dl[r]);
        if (flush) {
            float* row = agg + (size_t)dl[r] * FDIM;
            atomicAdd(row + lo,      c0);
            atomicAdd(row + 16 + lo, c1);
            atomicAdd(row + MUL0 + lo*3 + 0, c2);
            atomicAdd(row + MUL0 + lo*3 + 1, c3);
            atomicAdd(row + MUL0 + lo*3 + 2, c4);
            c0 = c1 = c2 = c3 = c4 = 0.f;
        }
    }
}

// ---------------------------------------------------------------------------
// Kernel 2: per-node epilogue over atomic agg (= d_out). 16 nodes/block.
// deg from CSR counts (int) -> no deg atomics in k_edge.
// ---------------------------------------------------------------------------
#define NPB 16
__global__ __launch_bounds__(256)
void k_node(const float* __restrict__ x,
            const int*   __restrict__ cnt,
            const float* __restrict__ ws_self,
            const float* __restrict__ wv_self,
            const float* __restrict__ ws_out,
            const float* __restrict__ wv_out,
            float* __restrict__ out)
{
    __shared__ float s_x[NPB][81];
    __shared__ float s_a[NPB][81];
    __shared__ float s_inv[NPB];

    const int tid = threadIdx.x;
    const int n0  = blockIdx.x * NPB;

    if (tid < NPB) s_inv[tid] = 1.0f / fmaxf((float)cnt[n0 + tid], 1.0f);
    const float* xb = x   + (size_t)n0 * FDIM;
    const float* ab = out + (size_t)n0 * FDIM;
    for (int idx = tid; idx < NPB * FDIM; idx += 256) {
        int nl = idx / FDIM, jj = idx - nl * FDIM;
        s_x[nl][jj] = xb[idx];
        s_a[nl][jj] = ab[idx];
    }
    __syncthreads();

    const int j  = tid & 15;
    const int nl = tid >> 4;
    const float inv = s_inv[nl];
    float* orow = out + (size_t)(n0 + nl) * FDIM;

    float s1s = 0.f, s1a = 0.f, s2s = 0.f, s2a = 0.f;
    #pragma unroll
    for (int i = 0; i < MUL0; ++i) {
        float xs = s_x[nl][i], as = s_a[nl][i];
        s1s += xs * ws_self[i * MUL0 + j];
        s1a += as * ws_out [i * MUL0 + j];
        s2s += xs * ws_self[i * MUL0 + j + 16];
        s2a += as * ws_out [i * MUL0 + j + 16];
    }
    orow[j]      = s1s + inv * s1a;
    orow[j + 16] = s2s + inv * s2a;

    float vs[3] = {0.f,0.f,0.f}, va[3] = {0.f,0.f,0.f};
    #pragma unroll
    for (int i = 0; i < MUL1; ++i) {
        float wsf = wv_self[i * MUL1 + j];
        float wof = wv_out [i * MUL1 + j];
        #pragma unroll
        for (int d = 0; d < 3; ++d) {
            vs[d] += s_x[nl][MUL0 + 3*i + d] * wsf;
            va[d] += s_a[nl][MUL0 + 3*i + d] * wof;
        }
    }
    #pragma unroll
    for (int d = 0; d < 3; ++d)
        orow[MUL0 + j*3 + d] = vs[d] + inv * va[d];
}

// ---------------------------------------------------------------------------
extern "C" void kernel_launch(void* const* d_in, const int* in_sizes, int n_in,
                              void* d_out, int out_size, void* d_ws, size_t ws_size,
                              hipStream_t stream)
{
    const float* x       = (const float*)d_in[0];
    const int*   esrc    = (const int*)  d_in[1];
    const int*   edst    = (const int*)  d_in[2];
    const float* esh     = (const float*)d_in[3];
    const float* erbf    = (const float*)d_in[4];
    const float* w1      = (const float*)d_in[5];
    const float* b1      = (const float*)d_in[6];
    const float* w2      = (const float*)d_in[7];
    const float* b2      = (const float*)d_in[8];
    const float* w3      = (const float*)d_in[9];
    const float* b3      = (const float*)d_in[10];
    const float* ws_self = (const float*)d_in[11];
    const float* wv_self = (const float*)d_in[12];
    const float* ws_out  = (const float*)d_in[13];
    const float* wv_out  = (const float*)d_in[14];

    const int N = in_sizes[0] / FDIM;   // 50000
    const int E = in_sizes[1];          // 200000
    const int NB = (N + 255) / 256;     // 196 scan blocks

    // ws layout (256B-aligned chunks)
    char* wsp = (char*)d_ws;
    size_t off = 0;
    auto take = [&](size_t bytes) {
        char* p = wsp + off;
        off += (bytes + 255) & ~(size_t)255;
        return p;
    };
    int* cnt    = (int*)take((size_t)N * 4);
    int* base   = (int*)take((size_t)N * 4);
    int* cursor = (int*)take((size_t)N * 4);
    int* bsum   = (int*)take((size_t)NB * 4);
    int* eidx   = (int*)take((size_t)E * 4);
    u16* w3n    = (u16*)take((size_t)W3N_ELEMS * 2);
    u16* w1b    = (u16*)take((size_t)W1B_ELEMS * 2);
    u16* w2b    = (u16*)take((size_t)W2B_ELEMS * 2);

    hipMemsetAsync(d_out, 0, (size_t)out_size * sizeof(float), stream);
    hipMemsetAsync(cnt, 0, (size_t)N * 4, stream);
    hipMemsetAsync(cursor, 0, (size_t)N * 4, stream);

    k_prep<<<(W3N_ELEMS + W1B_ELEMS + W2B_ELEMS + 255) / 256, 256, 0, stream>>>(
        w3, w1, w2, w3n, w1b, w2b);

    k_cnt      <<<(E + 255) / 256, 256, 0, stream>>>(edst, cnt, E);
    k_scan_part<<<NB, 256, 0, stream>>>(cnt, bsum, N);
    k_scan_top <<<1, 256, 0, stream>>>(bsum, NB);
    k_scan_base<<<NB, 256, 0, stream>>>(cnt, bsum, base, N);
    k_fill     <<<(E + 255) / 256, 256, 0, stream>>>(edst, base, cursor, eidx, E);

    const int nblk = (E + TE - 1) / TE;
    k_edge<<<nblk, NTHREADS, 0, stream>>>(
        x, esrc, edst, esh, erbf, eidx, w1b, b1, w2b, b2, w3n, b3,
        (float*)d_out, E);

    k_node<<<N / NPB, 256, 0, stream>>>(
        x, cnt, ws_self, wv_self, ws_out, wv_out, (float*)d_out);
}

// Round 21
// 231.188 us; speedup vs baseline: 1.0174x; 1.0174x over previous
//
#include <hip/hip_runtime.h>
#include <math.h>

// Problem constants (fixed by reference)
#define MUL0    32
#define MUL1    16
#define RBFD    16
#define HIDD    64
#define WNUMEL  2304
#define FDIM    80
#define CPATH   0.14433756729740643f   // 1/sqrt(48)
#define C110    0.57735026918962576f   // 1/sqrt(3)

#define TE       128      // edges per block (8 waves x 16 edges)
#define NTHREADS 512
#define NITER    48       // column-tile iterations (divisible by 3)

#define W3N_ELEMS (NITER*6*512)    // 147456 u16 (consumption-ordered, CPATH-folded)
#define W1B_ELEMS (4*64*8)         // 2048
#define W2B_ELEMS (4*2*64*8)       // 4096

// k_edge LDS byte map (37,376 B)
#define FS4_U16  0
#define XS_U16   2048
#define XV_U16   6144
#define SH_B     24576             // f32[128][4] -> 26624
#define SRC_B    26624             // int[128]    -> 27136
#define DST_B    27136             // int[128]    -> 27648
#define B3_B     27648             // f32[2304] (reordered, CPATH-folded) -> 36864
#define EID_B    36864             // int[128]    -> 37376
#define SMEM_B   37376

typedef float          f32x4   __attribute__((ext_vector_type(4)));
typedef short          short8  __attribute__((ext_vector_type(8)));
typedef short          short4v __attribute__((ext_vector_type(4)));
typedef unsigned short u16;

__device__ __forceinline__ float silu(float v) {
    return v / (1.0f + __expf(-v));
}
__device__ __forceinline__ u16 f2bf(float f) {      // RNE fp32->bf16
    unsigned int u = __float_as_uint(f);
    u += 0x7fffu + ((u >> 16) & 1u);
    return (u16)(u >> 16);
}
__device__ __forceinline__ float bf2f(u16 s) {
    return __uint_as_float(((unsigned int)s) << 16);
}
__device__ __forceinline__ f32x4 cvt4(short4v s) {
    f32x4 r;
    r[0] = bf2f((u16)s[0]); r[1] = bf2f((u16)s[1]);
    r[2] = bf2f((u16)s[2]); r[3] = bf2f((u16)s[3]);
    return r;
}
__device__ __forceinline__ f32x4 mfma16(short8 a, short8 b, f32x4 c) {
    return __builtin_amdgcn_mfma_f32_16x16x32_bf16(a, b, c, 0, 0, 0);
}

// iteration t, pair p (0,1 -> 32-col halves; 2 -> 16-col tile) -> column tile
__device__ __forceinline__ int tile_of(int t, int pair) {
    if (t < 32) return (pair == 0) ? 2*t : (pair == 1) ? 2*t + 1 : 64 + t;
    int tt = t - 32;
    return (pair == 0) ? 112 + 2*tt : (pair == 1) ? 113 + 2*tt : 96 + tt;
}

// ---------------------------------------------------------------------------
// Kernel 0: pack w3 (x CPATH) into consumption-ordered bf16 fragments + w1b/w2b.
// ---------------------------------------------------------------------------
__global__ void k_prep(const float* __restrict__ w3,
                       const float* __restrict__ w1,
                       const float* __restrict__ w2,
                       u16* __restrict__ w3n,
                       u16* __restrict__ w1b,
                       u16* __restrict__ w2b) {
    int idx = blockIdx.x * 256 + threadIdx.x;
    if (idx < W3N_ELEMS) {
        int j = idx & 7, l = (idx >> 3) & 63, f = idx >> 9;
        int t = f / 6, s = f - 6 * t, pair = s >> 1, kh = s & 1;
        int tile = tile_of(t, pair);
        int k = kh * 32 + 8 * (l >> 4) + j;
        int c = tile * 16 + (l & 15);
        w3n[idx] = f2bf(CPATH * w3[k * WNUMEL + c]);
        return;
    }
    idx -= W3N_ELEMS;
    if (idx < W1B_ELEMS) {
        int j = idx & 7, l = (idx >> 3) & 63, ct = idx >> 9;
        int k = 8 * (l >> 4) + j;
        int c = ct * 16 + (l & 15);
        w1b[idx] = (k < RBFD) ? f2bf(w1[k * HIDD + c]) : (u16)0;
        return;
    }
    idx -= W1B_ELEMS;
    if (idx < W2B_ELEMS) {
        int j = idx & 7, l = (idx >> 3) & 63, kh = (idx >> 9) & 1, ct = idx >> 10;
        int k = kh * 32 + 8 * (l >> 4) + j;
        int c = ct * 16 + (l & 15);
        w2b[idx] = f2bf(w2[k * HIDD + c]);
    }
}

// ---------------------------------------------------------------------------
// CSR build: count -> PARALLEL hierarchical scan -> fill
// ---------------------------------------------------------------------------
__global__ void k_cnt(const int* __restrict__ edst, int* __restrict__ cnt, int E) {
    int e = blockIdx.x * 256 + threadIdx.x;
    if (e < E) atomicAdd(&cnt[edst[e]], 1);
}

// per-block reduction: bsum[b] = sum of cnt[b*256 .. b*256+255]
__global__ __launch_bounds__(256)
void k_scan_part(const int* __restrict__ cnt, int* __restrict__ bsum, int N) {
    __shared__ int sh[256];
    int i = blockIdx.x * 256 + threadIdx.x;
    sh[threadIdx.x] = (i < N) ? cnt[i] : 0;
    __syncthreads();
    for (int off = 128; off > 0; off >>= 1) {
        if (threadIdx.x < off) sh[threadIdx.x] += sh[threadIdx.x + off];
        __syncthreads();
    }
    if (threadIdx.x == 0) bsum[blockIdx.x] = sh[0];
}

// single small block: exclusive scan of nb (<=256) block sums, in place
__global__ __launch_bounds__(256)
void k_scan_top(int* __restrict__ bsum, int nb) {
    __shared__ int sh[256];
    const int t = threadIdx.x;
    int orig = (t < nb) ? bsum[t] : 0;
    sh[t] = orig;
    __syncthreads();
    for (int off = 1; off < 256; off <<= 1) {
        int v = (t >= off) ? sh[t - off] : 0;
        __syncthreads();
        sh[t] += v;
        __syncthreads();
    }
    if (t < nb) bsum[t] = sh[t] - orig;   // exclusive
}

// per-block exclusive scan + block offset -> base
__global__ __launch_bounds__(256)
void k_scan_base(const int* __restrict__ cnt, const int* __restrict__ bsum,
                 int* __restrict__ base, int N) {
    __shared__ int sh[256];
    const int t = threadIdx.x;
    int i = blockIdx.x * 256 + t;
    int orig = (i < N) ? cnt[i] : 0;
    sh[t] = orig;
    __syncthreads();
    for (int off = 1; off < 256; off <<= 1) {
        int v = (t >= off) ? sh[t - off] : 0;
        __syncthreads();
        sh[t] += v;
        __syncthreads();
    }
    if (i < N) base[i] = bsum[blockIdx.x] + sh[t] - orig;
}

__global__ void k_fill(const int* __restrict__ edst,
                       const int* __restrict__ base,
                       int* __restrict__ cursor,
                       int* __restrict__ eidx, int E) {
    int e = blockIdx.x * 256 + threadIdx.x;
    if (e < E) {
        int d = edst[e];
        int p = atomicAdd(&cursor[d], 1);
        eidx[base[d] + p] = e;
    }
}

// one column-tile iteration's compute for this wave's single 16-edge row-tile
#define COMPUTE(T, BP) do {                                                    \
    float bs0 = s_b3[(T)*48 + lo];                                             \
    float bs1 = s_b3[(T)*48 + 16 + lo];                                        \
    float bs2 = s_b3[(T)*48 + 32 + lo];                                        \
    f32x4 tA = {bs0,bs0,bs0,bs0};                                              \
    tA = mfma16(a0, BP[0], tA); tA = mfma16(a1, BP[1], tA);                    \
    f32x4 tB = {bs1,bs1,bs1,bs1};                                              \
    tB = mfma16(a0, BP[2], tB); tB = mfma16(a1, BP[3], tB);                    \
    f32x4 tC = {bs2,bs2,bs2,bs2};                                              \
    tC = mfma16(a0, BP[4], tC); tC = mfma16(a1, BP[5], tC);                    \
    if ((T) < 32) {                                                            \
        f32x4 fx = cvt4(*(const short4v*)&S[XS_U16 + w*512 + (T)*16 + 4*g]);   \
        f32x4 f1 = fx * sh0v;                                                  \
        acc[0] += f1 * tA;                                                     \
        acc[1] += f1 * tB;                                                     \
        acc[2] += fx * tC;                                                     \
    } else {                                                                   \
        const int i_ = (T) - 32;                                               \
        f32x4 f4 = cvt4(*(const short4v*)&S[FS4_U16 + w*256 + i_*16 + 4*g]);   \
        acc[0] += f4 * tA;                                                     \
        acc[1] += f4 * tB;                                                     \
        acc[3] += cvt4(*(const short4v*)&S[XV_U16 + w*768 + (0 +i_)*16 + 4*g]) * tC; \
        acc[4] += cvt4(*(const short4v*)&S[XV_U16 + w*768 + (16+i_)*16 + 4*g]) * tC; \
        acc[5] += cvt4(*(const short4v*)&S[XV_U16 + w*768 + (32+i_)*16 + 4*g]) * tC; \
    }                                                                          \
} while (0)

// ---------------------------------------------------------------------------
// Kernel 1: MFMA MLP + fused W-tile contraction + run-combined atomic scatter.
// Champion structure (R19): 8 waves x 16 edges, depth-3 register pipeline
// (VGPR=64, 8 waves/SIMD quantum), dst-sorted (CSR) edge order, free-running.
// ---------------------------------------------------------------------------
__global__ __launch_bounds__(NTHREADS, 4)
void k_edge(const float* __restrict__ x,
            const int*   __restrict__ esrc,
            const int*   __restrict__ edst,
            const float* __restrict__ esh,
            const float* __restrict__ erbf,
            const int*   __restrict__ eidx,
            const u16*   __restrict__ w1b,
            const float* __restrict__ b1,
            const u16*   __restrict__ w2b,
            const float* __restrict__ b2,
            const u16*   __restrict__ w3n,
            const float* __restrict__ b3,
            float* __restrict__ agg,
            int E)
{
    __shared__ alignas(16) unsigned char smem[SMEM_B];
    u16*   S     = (u16*)smem;            // features; MLP-phase alias s_hb[128][72]
    float* s_sh  = (float*)(smem + SH_B);
    int*   s_src = (int*)(smem + SRC_B);
    int*   s_dst = (int*)(smem + DST_B);
    float* s_b3  = (float*)(smem + B3_B);
    int*   s_eid = (int*)(smem + EID_B);

    const int tid = threadIdx.x;
    const int eb  = blockIdx.x * TE;
    const int w   = tid >> 6;        // wave 0..7, owns edges 16w..16w+15
    const int l   = tid & 63;
    const int lo  = l & 15;
    const int g   = l >> 4;

    // ---- stage edge metadata in CSR order (guarded; last block partial) ----
    if (tid < TE) {
        int eg  = eb + tid;
        int eid = (eg < E) ? eidx[eg] : 0;
        s_eid[tid] = eid;
        s_src[tid] = esrc[eid];
        s_dst[tid] = (eg < E) ? edst[eid] : 0;
        f32x4 sh4 = {0.f, 0.f, 0.f, 0.f};
        if (eg < E) sh4 = *(const f32x4*)(esh + (size_t)eid * 4);
        *(f32x4*)&s_sh[tid * 4] = sh4;     // sh=0 zeroes pad-edge output
    }
    __syncthreads();

    // ---- MLP (MFMA): rbf -> h1 -> h (bf16 rows, stride 72, wave-private) ----
    float cb1[4], cb2[4];
    #pragma unroll
    for (int ct = 0; ct < 4; ++ct) { cb1[ct] = b1[ct*16 + lo]; cb2[ct] = b2[ct*16 + lo]; }
    const short8* W1B = (const short8*)w1b;
    const short8* W2B = (const short8*)w2b;
    const int e0 = 16 * w;

    {
        short8 ar = {0,0,0,0,0,0,0,0};
        if (g < 2 && (eb + e0 + lo) < E) {
            const float* rp = erbf + (size_t)s_eid[e0 + lo] * RBFD + 8 * g;
            f32x4 r0 = *(const f32x4*)rp;
            f32x4 r1 = *(const f32x4*)(rp + 4);
            ar[0]=f2bf(r0[0]); ar[1]=f2bf(r0[1]); ar[2]=f2bf(r0[2]); ar[3]=f2bf(r0[3]);
            ar[4]=f2bf(r1[0]); ar[5]=f2bf(r1[1]); ar[6]=f2bf(r1[2]); ar[7]=f2bf(r1[3]);
        }
        #pragma unroll
        for (int ct = 0; ct < 4; ++ct) {
            f32x4 t = {cb1[ct], cb1[ct], cb1[ct], cb1[ct]};
            t = mfma16(ar, W1B[ct * 64 + l], t);
            #pragma unroll
            for (int r = 0; r < 4; ++r)
                S[(e0 + 4*g + r) * 72 + ct*16 + lo] = f2bf(silu(t[r]));
        }
    }
    {
        short8 h0 = *(const short8*)&S[(e0 + lo) * 72 + 0  + 8*g];
        short8 h1 = *(const short8*)&S[(e0 + lo) * 72 + 32 + 8*g];
        #pragma unroll
        for (int ct = 0; ct < 4; ++ct) {
            f32x4 t = {cb2[ct], cb2[ct], cb2[ct], cb2[ct]};
            t = mfma16(h0, W2B[(ct*2 + 0) * 64 + l], t);
            t = mfma16(h1, W2B[(ct*2 + 1) * 64 + l], t);
            #pragma unroll
            for (int r = 0; r < 4; ++r)
                S[(e0 + 4*g + r) * 72 + ct*16 + lo] = f2bf(silu(t[r]));
        }
    }
    // A-fragments for the main loop (this wave's single row-tile)
    short8 a0 = *(const short8*)&S[(e0 + lo) * 72 + 0  + 8*g];
    short8 a1 = *(const short8*)&S[(e0 + lo) * 72 + 32 + 8*g];
    __syncthreads();   // h rows dead; feature region may overwrite

    // ---- features (bf16) + reordered CPATH-folded b3 staging ----
    if (tid < TE) {
        const int el = tid, grp = el >> 4, e16 = el & 15;
        const float sh0 = s_sh[el*4 + 0];
        const float sh1 = s_sh[el*4 + 1];
        const float sh2 = s_sh[el*4 + 2];
        const float sh3 = s_sh[el*4 + 3];
        const float* xrow = x + (size_t)s_src[el] * FDIM;
        u16* fs4B = S + FS4_U16 + grp * 256 + e16;   // W4 path (C110 * xv.shv)
        u16* xsB  = S + XS_U16  + grp * 512 + e16;   // raw xs (sh_s folded at use)
        u16* xvB  = S + XV_U16  + grp * 768 + e16;   // xv * sh_s
        #pragma unroll
        for (int v = 0; v < 8; ++v) {
            f32x4 x4 = *(const f32x4*)(xrow + 4 * v);
            #pragma unroll
            for (int c2 = 0; c2 < 4; ++c2)
                xsB[(4 * v + c2) * 16] = f2bf(x4[c2]);
        }
        float buf[48];
        #pragma unroll
        for (int v = 0; v < 12; ++v) {
            f32x4 t4 = *(const f32x4*)(xrow + MUL0 + 4 * v);
            buf[4*v]=t4[0]; buf[4*v+1]=t4[1]; buf[4*v+2]=t4[2]; buf[4*v+3]=t4[3];
        }
        #pragma unroll
        for (int i = 0; i < 16; ++i) {
            float v0 = buf[3*i], v1 = buf[3*i+1], v2 = buf[3*i+2];
            xvB[(0  + i) * 16] = f2bf(v0 * sh0);
            xvB[(16 + i) * 16] = f2bf(v1 * sh0);
            xvB[(32 + i) * 16] = f2bf(v2 * sh0);
            fs4B[i * 16]       = f2bf(C110 * (v0*sh1 + v1*sh2 + v2*sh3));
        }
    } else {
        for (int idx = tid - TE; idx < WNUMEL; idx += NTHREADS - TE) {
            int t = idx / 48, r = idx - 48 * t, pair = r >> 4, lo16 = r & 15;
            s_b3[idx] = CPATH * b3[tile_of(t, pair) * 16 + lo16];
        }
    }
    __syncthreads();

    // per-thread sh_s broadcast for the W1-path fold (4 edges per lane-group)
    f32x4 sh0v;
    #pragma unroll
    for (int r = 0; r < 4; ++r)
        sh0v[r] = s_sh[(16*w + 4*g + r) * 4];

    // ---- main loop: DEPTH-3 register pipeline, uniform distance, free-run ----
    const short8* WB = (const short8*)w3n;
    f32x4 acc[6];
    #pragma unroll
    for (int p = 0; p < 6; ++p) acc[p] = (f32x4){0.f,0.f,0.f,0.f};

    short8 p0[6], p1[6], p2[6];
    #pragma unroll
    for (int s = 0; s < 6; ++s) {
        p0[s] = WB[0*384 + s*64 + l];
        p1[s] = WB[1*384 + s*64 + l];
        p2[s] = WB[2*384 + s*64 + l];
    }

    for (int t = 0; t < NITER; t += 3) {
        COMPUTE(t, p0);
        {   const int tn = (t + 3 < NITER) ? (t + 3) : 0;   // wrap: result unused
            #pragma unroll
            for (int s = 0; s < 6; ++s) p0[s] = WB[tn*384 + s*64 + l];
        }
        COMPUTE(t + 1, p1);
        {   const int tn = (t + 4 < NITER) ? (t + 4) : 0;
            #pragma unroll
            for (int s = 0; s < 6; ++s) p1[s] = WB[tn*384 + s*64 + l];
        }
        COMPUTE(t + 2, p2);
        {   const int tn = (t + 5 < NITER) ? (t + 5) : 0;
            #pragma unroll
            for (int s = 0; s < 6; ++s) p2[s] = WB[tn*384 + s*64 + l];
        }
    }

    // ---- epilogue: run-combined atomic scatter (CSR order -> equal dst runs)
    int   dl[4];
    float o0[4], o1[4], o2[4], o3[4], o4[4];
    #pragma unroll
    for (int r = 0; r < 4; ++r) {
        const int e_loc = 16*w + 4*g + r;
        dl[r] = s_dst[e_loc];
        float sv0 = s_sh[e_loc*4 + 1];
        float sv1 = s_sh[e_loc*4 + 2];
        float sv2 = s_sh[e_loc*4 + 3];
        o0[r] = acc[0][r];
        o1[r] = acc[1][r];
        o2[r] = sv0*acc[2][r] + acc[3][r];
        o3[r] = sv1*acc[2][r] + acc[4][r];
        o4[r] = sv2*acc[2][r] + acc[5][r];
    }
    float c0 = 0.f, c1 = 0.f, c2 = 0.f, c3 = 0.f, c4 = 0.f;
    #pragma unroll
    for (int r = 0; r < 4; ++r) {
        c0 += o0[r]; c1 += o1[r]; c2 += o2[r]; c3 += o3[r]; c4 += o4[r];
        bool flush = (r == 3) || (dl[r + 1] != dl[r]);
        if (flush) {
            float* row = agg + (size_t)dl[r] * FDIM;
            atomicAdd(row + lo,      c0);
            atomicAdd(row + 16 + lo, c1);
            atomicAdd(row + MUL0 + lo*3 + 0, c2);
            atomicAdd(row + MUL0 + lo*3 + 1, c3);
            atomicAdd(row + MUL0 + lo*3 + 2, c4);
            c0 = c1 = c2 = c3 = c4 = 0.f;
        }
    }
}

// ---------------------------------------------------------------------------
// Kernel 2: per-node epilogue over atomic agg (= d_out). 16 nodes/block.
// deg from CSR counts (int) -> no deg atomics in k_edge.
// ---------------------------------------------------------------------------
#define NPB 16
__global__ __launch_bounds__(256)
void k_node(const float* __restrict__ x,
            const int*   __restrict__ cnt,
            const float* __restrict__ ws_self,
            const float* __restrict__ wv_self,
            const float* __restrict__ ws_out,
            const float* __restrict__ wv_out,
            float* __restrict__ out)
{
    __shared__ float s_x[NPB][81];
    __shared__ float s_a[NPB][81];
    __shared__ float s_inv[NPB];

    const int tid = threadIdx.x;
    const int n0  = blockIdx.x * NPB;

    if (tid < NPB) s_inv[tid] = 1.0f / fmaxf((float)cnt[n0 + tid], 1.0f);
    const float* xb = x   + (size_t)n0 * FDIM;
    const float* ab = out + (size_t)n0 * FDIM;
    for (int idx = tid; idx < NPB * FDIM; idx += 256) {
        int nl = idx / FDIM, jj = idx - nl * FDIM;
        s_x[nl][jj] = xb[idx];
        s_a[nl][jj] = ab[idx];
    }
    __syncthreads();

    const int j  = tid & 15;
    const int nl = tid >> 4;
    const float inv = s_inv[nl];
    float* orow = out + (size_t)(n0 + nl) * FDIM;

    float s1s = 0.f, s1a = 0.f, s2s = 0.f, s2a = 0.f;
    #pragma unroll
    for (int i = 0; i < MUL0; ++i) {
        float xs = s_x[nl][i], as = s_a[nl][i];
        s1s += xs * ws_self[i * MUL0 + j];
        s1a += as * ws_out [i * MUL0 + j];
        s2s += xs * ws_self[i * MUL0 + j + 16];
        s2a += as * ws_out [i * MUL0 + j + 16];
    }
    orow[j]      = s1s + inv * s1a;
    orow[j + 16] = s2s + inv * s2a;

    float vs[3] = {0.f,0.f,0.f}, va[3] = {0.f,0.f,0.f};
    #pragma unroll
    for (int i = 0; i < MUL1; ++i) {
        float wsf = wv_self[i * MUL1 + j];
        float wof = wv_out [i * MUL1 + j];
        #pragma unroll
        for (int d = 0; d < 3; ++d) {
            vs[d] += s_x[nl][MUL0 + 3*i + d] * wsf;
            va[d] += s_a[nl][MUL0 + 3*i + d] * wof;
        }
    }
    #pragma unroll
    for (int d = 0; d < 3; ++d)
        orow[MUL0 + j*3 + d] = vs[d] + inv * va[d];
}

// ---------------------------------------------------------------------------
extern "C" void kernel_launch(void* const* d_in, const int* in_sizes, int n_in,
                              void* d_out, int out_size, void* d_ws, size_t ws_size,
                              hipStream_t stream)
{
    const float* x       = (const float*)d_in[0];
    const int*   esrc    = (const int*)  d_in[1];
    const int*   edst    = (const int*)  d_in[2];
    const float* esh     = (const float*)d_in[3];
    const float* erbf    = (const float*)d_in[4];
    const float* w1      = (const float*)d_in[5];
    const float* b1      = (const float*)d_in[6];
    const float* w2      = (const float*)d_in[7];
    const float* b2      = (const float*)d_in[8];
    const float* w3      = (const float*)d_in[9];
    const float* b3      = (const float*)d_in[10];
    const float* ws_self = (const float*)d_in[11];
    const float* wv_self = (const float*)d_in[12];
    const float* ws_out  = (const float*)d_in[13];
    const float* wv_out  = (const float*)d_in[14];

    const int N = in_sizes[0] / FDIM;   // 50000
    const int E = in_sizes[1];          // 200000
    const int NB = (N + 255) / 256;     // 196 scan blocks

    // ws layout (256B-aligned chunks)
    char* wsp = (char*)d_ws;
    size_t off = 0;
    auto take = [&](size_t bytes) {
        char* p = wsp + off;
        off += (bytes + 255) & ~(size_t)255;
        return p;
    };
    int* cnt    = (int*)take((size_t)N * 4);
    int* base   = (int*)take((size_t)N * 4);
    int* cursor = (int*)take((size_t)N * 4);
    int* bsum   = (int*)take((size_t)NB * 4);
    int* eidx   = (int*)take((size_t)E * 4);
    u16* w3n    = (u16*)take((size_t)W3N_ELEMS * 2);
    u16* w1b    = (u16*)take((size_t)W1B_ELEMS * 2);
    u16* w2b    = (u16*)take((size_t)W2B_ELEMS * 2);

    hipMemsetAsync(d_out, 0, (size_t)out_size * sizeof(float), stream);
    hipMemsetAsync(cnt, 0, (size_t)N * 4, stream);
    hipMemsetAsync(cursor, 0, (size_t)N * 4, stream);

    k_prep<<<(W3N_ELEMS + W1B_ELEMS + W2B_ELEMS + 255) / 256, 256, 0, stream>>>(
        w3, w1, w2, w3n, w1b, w2b);

    k_cnt      <<<(E + 255) / 256, 256, 0, stream>>>(edst, cnt, E);
    k_scan_part<<<NB, 256, 0, stream>>>(cnt, bsum, N);
    k_scan_top <<<1, 256, 0, stream>>>(bsum, NB);
    k_scan_base<<<NB, 256, 0, stream>>>(cnt, bsum, base, N);
    k_fill     <<<(E + 255) / 256, 256, 0, stream>>>(edst, base, cursor, eidx, E);

    const int nblk = (E + TE - 1) / TE;
    k_edge<<<nblk, NTHREADS, 0, stream>>>(
        x, esrc, edst, esh, erbf, eidx, w1b, b1, w2b, b2, w3n, b3,
        (float*)d_out, E);

    k_node<<<N / NPB, 256, 0, stream>>>(
        x, cnt, ws_self, wv_self, ws_out, wv_out, (float*)d_out);
}

// Round 22
// 230.201 us; speedup vs baseline: 1.0218x; 1.0043x over previous
//
#include <hip/hip_runtime.h>
#include <math.h>

// Problem constants (fixed by reference)
#define MUL0    32
#define MUL1    16
#define RBFD    16
#define HIDD    64
#define WNUMEL  2304
#define FDIM    80
#define CPATH   0.14433756729740643f   // 1/sqrt(48)
#define C110    0.57735026918962576f   // 1/sqrt(3)

#define TE       128      // edges per block (8 waves x 16 edges)
#define NTHREADS 512
#define NITER    48       // column-tile iterations (divisible by 3)

#define W3N_ELEMS (NITER*6*512)    // 147456 u16 (consumption-ordered, CPATH-folded)
#define W1B_ELEMS (4*64*8)         // 2048
#define W2B_ELEMS (4*2*64*8)       // 4096

// k_edge LDS byte map (37,376 B)
#define FS4_U16  0
#define XS_U16   2048
#define XV_U16   6144
#define SH_B     24576             // f32[128][4] -> 26624
#define SRC_B    26624             // int[128]    -> 27136
#define DST_B    27136             // int[128]    -> 27648
#define B3_B     27648             // f32[2304] (reordered, CPATH-folded) -> 36864
#define EID_B    36864             // int[128]    -> 37376
#define SMEM_B   37376

typedef float          f32x4   __attribute__((ext_vector_type(4)));
typedef short          short8  __attribute__((ext_vector_type(8)));
typedef short          short4v __attribute__((ext_vector_type(4)));
typedef unsigned short u16;

__device__ __forceinline__ float silu(float v) {
    return v / (1.0f + __expf(-v));
}
__device__ __forceinline__ u16 f2bf(float f) {      // RNE fp32->bf16
    unsigned int u = __float_as_uint(f);
    u += 0x7fffu + ((u >> 16) & 1u);
    return (u16)(u >> 16);
}
__device__ __forceinline__ float bf2f(u16 s) {
    return __uint_as_float(((unsigned int)s) << 16);
}
__device__ __forceinline__ f32x4 cvt4(short4v s) {
    f32x4 r;
    r[0] = bf2f((u16)s[0]); r[1] = bf2f((u16)s[1]);
    r[2] = bf2f((u16)s[2]); r[3] = bf2f((u16)s[3]);
    return r;
}
__device__ __forceinline__ f32x4 mfma16(short8 a, short8 b, f32x4 c) {
    return __builtin_amdgcn_mfma_f32_16x16x32_bf16(a, b, c, 0, 0, 0);
}

// iteration t, pair p (0,1 -> 32-col halves; 2 -> 16-col tile) -> column tile
__device__ __forceinline__ int tile_of(int t, int pair) {
    if (t < 32) return (pair == 0) ? 2*t : (pair == 1) ? 2*t + 1 : 64 + t;
    int tt = t - 32;
    return (pair == 0) ? 112 + 2*tt : (pair == 1) ? 113 + 2*tt : 96 + tt;
}

// ---------------------------------------------------------------------------
// Kernel 0: pack w3 (x CPATH) into consumption-ordered bf16 fragments + w1b/w2b.
// ---------------------------------------------------------------------------
__global__ void k_prep(const float* __restrict__ w3,
                       const float* __restrict__ w1,
                       const float* __restrict__ w2,
                       u16* __restrict__ w3n,
                       u16* __restrict__ w1b,
                       u16* __restrict__ w2b) {
    int idx = blockIdx.x * 256 + threadIdx.x;
    if (idx < W3N_ELEMS) {
        int j = idx & 7, l = (idx >> 3) & 63, f = idx >> 9;
        int t = f / 6, s = f - 6 * t, pair = s >> 1, kh = s & 1;
        int tile = tile_of(t, pair);
        int k = kh * 32 + 8 * (l >> 4) + j;
        int c = tile * 16 + (l & 15);
        w3n[idx] = f2bf(CPATH * w3[k * WNUMEL + c]);
        return;
    }
    idx -= W3N_ELEMS;
    if (idx < W1B_ELEMS) {
        int j = idx & 7, l = (idx >> 3) & 63, ct = idx >> 9;
        int k = 8 * (l >> 4) + j;
        int c = ct * 16 + (l & 15);
        w1b[idx] = (k < RBFD) ? f2bf(w1[k * HIDD + c]) : (u16)0;
        return;
    }
    idx -= W1B_ELEMS;
    if (idx < W2B_ELEMS) {
        int j = idx & 7, l = (idx >> 3) & 63, kh = (idx >> 9) & 1, ct = idx >> 10;
        int k = kh * 32 + 8 * (l >> 4) + j;
        int c = ct * 16 + (l & 15);
        w2b[idx] = f2bf(w2[k * HIDD + c]);
    }
}

// ---------------------------------------------------------------------------
// CSR build: count -> PARALLEL hierarchical scan -> fill
// ---------------------------------------------------------------------------
__global__ void k_cnt(const int* __restrict__ edst, int* __restrict__ cnt, int E) {
    int e = blockIdx.x * 256 + threadIdx.x;
    if (e < E) atomicAdd(&cnt[edst[e]], 1);
}

// per-block reduction: bsum[b] = sum of cnt[b*256 .. b*256+255]
__global__ __launch_bounds__(256)
void k_scan_part(const int* __restrict__ cnt, int* __restrict__ bsum, int N) {
    __shared__ int sh[256];
    int i = blockIdx.x * 256 + threadIdx.x;
    sh[threadIdx.x] = (i < N) ? cnt[i] : 0;
    __syncthreads();
    for (int off = 128; off > 0; off >>= 1) {
        if (threadIdx.x < off) sh[threadIdx.x] += sh[threadIdx.x + off];
        __syncthreads();
    }
    if (threadIdx.x == 0) bsum[blockIdx.x] = sh[0];
}

// single small block: exclusive scan of nb (<=256) block sums, in place
__global__ __launch_bounds__(256)
void k_scan_top(int* __restrict__ bsum, int nb) {
    __shared__ int sh[256];
    const int t = threadIdx.x;
    int orig = (t < nb) ? bsum[t] : 0;
    sh[t] = orig;
    __syncthreads();
    for (int off = 1; off < 256; off <<= 1) {
        int v = (t >= off) ? sh[t - off] : 0;
        __syncthreads();
        sh[t] += v;
        __syncthreads();
    }
    if (t < nb) bsum[t] = sh[t] - orig;   // exclusive
}

// per-block exclusive scan + block offset -> base
__global__ __launch_bounds__(256)
void k_scan_base(const int* __restrict__ cnt, const int* __restrict__ bsum,
                 int* __restrict__ base, int N) {
    __shared__ int sh[256];
    const int t = threadIdx.x;
    int i = blockIdx.x * 256 + t;
    int orig = (i < N) ? cnt[i] : 0;
    sh[t] = orig;
    __syncthreads();
    for (int off = 1; off < 256; off <<= 1) {
        int v = (t >= off) ? sh[t - off] : 0;
        __syncthreads();
        sh[t] += v;
        __syncthreads();
    }
    if (i < N) base[i] = bsum[blockIdx.x] + sh[t] - orig;
}

__global__ void k_fill(const int* __restrict__ edst,
                       const int* __restrict__ base,
                       int* __restrict__ cursor,
                       int* __restrict__ eidx, int E) {
    int e = blockIdx.x * 256 + threadIdx.x;
    if (e < E) {
        int d = edst[e];
        int p = atomicAdd(&cursor[d], 1);
        eidx[base[d] + p] = e;
    }
}

// one column-tile iteration's compute for this wave's single 16-edge row-tile
#define COMPUTE(T, BP) do {                                                    \
    float bs0 = s_b3[(T)*48 + lo];                                             \
    float bs1 = s_b3[(T)*48 + 16 + lo];                                        \
    float bs2 = s_b3[(T)*48 + 32 + lo];                                        \
    f32x4 tA = {bs0,bs0,bs0,bs0};                                              \
    tA = mfma16(a0, BP[0], tA); tA = mfma16(a1, BP[1], tA);                    \
    f32x4 tB = {bs1,bs1,bs1,bs1};                                              \
    tB = mfma16(a0, BP[2], tB); tB = mfma16(a1, BP[3], tB);                    \
    f32x4 tC = {bs2,bs2,bs2,bs2};                                              \
    tC = mfma16(a0, BP[4], tC); tC = mfma16(a1, BP[5], tC);                    \
    if ((T) < 32) {                                                            \
        f32x4 fx = cvt4(*(const short4v*)&S[XS_U16 + w*512 + (T)*16 + 4*g]);   \
        f32x4 f1 = fx * sh0v;                                                  \
        acc[0] += f1 * tA;                                                     \
        acc[1] += f1 * tB;                                                     \
        acc[2] += fx * tC;                                                     \
    } else {                                                                   \
        const int i_ = (T) - 32;                                               \
        f32x4 f4 = cvt4(*(const short4v*)&S[FS4_U16 + w*256 + i_*16 + 4*g]);   \
        acc[0] += f4 * tA;                                                     \
        acc[1] += f4 * tB;                                                     \
        acc[3] += cvt4(*(const short4v*)&S[XV_U16 + w*768 + (0 +i_)*16 + 4*g]) * tC; \
        acc[4] += cvt4(*(const short4v*)&S[XV_U16 + w*768 + (16+i_)*16 + 4*g]) * tC; \
        acc[5] += cvt4(*(const short4v*)&S[XV_U16 + w*768 + (32+i_)*16 + 4*g]) * tC; \
    }                                                                          \
} while (0)

// ---------------------------------------------------------------------------
// Kernel 1: MFMA MLP + fused W-tile contraction + run-combined atomic scatter.
// Champion structure (R19): 8 waves x 16 edges, depth-3 register pipeline
// (VGPR=64, 8 waves/SIMD quantum), dst-sorted (CSR) edge order, free-running.
// ---------------------------------------------------------------------------
__global__ __launch_bounds__(NTHREADS, 4)
void k_edge(const float* __restrict__ x,
            const int*   __restrict__ esrc,
            const int*   __restrict__ edst,
            const float* __restrict__ esh,
            const float* __restrict__ erbf,
            const int*   __restrict__ eidx,
            const u16*   __restrict__ w1b,
            const float* __restrict__ b1,
            const u16*   __restrict__ w2b,
            const float* __restrict__ b2,
            const u16*   __restrict__ w3n,
            const float* __restrict__ b3,
            float* __restrict__ agg,
            int E)
{
    __shared__ alignas(16) unsigned char smem[SMEM_B];
    u16*   S     = (u16*)smem;            // features; MLP-phase alias s_hb[128][72]
    float* s_sh  = (float*)(smem + SH_B);
    int*   s_src = (int*)(smem + SRC_B);
    int*   s_dst = (int*)(smem + DST_B);
    float* s_b3  = (float*)(smem + B3_B);
    int*   s_eid = (int*)(smem + EID_B);

    const int tid = threadIdx.x;
    const int eb  = blockIdx.x * TE;
    const int w   = tid >> 6;        // wave 0..7, owns edges 16w..16w+15
    const int l   = tid & 63;
    const int lo  = l & 15;
    const int g   = l >> 4;

    // ---- stage edge metadata in CSR order (guarded; last block partial) ----
    if (tid < TE) {
        int eg  = eb + tid;
        int eid = (eg < E) ? eidx[eg] : 0;
        s_eid[tid] = eid;
        s_src[tid] = esrc[eid];
        s_dst[tid] = (eg < E) ? edst[eid] : 0;
        f32x4 sh4 = {0.f, 0.f, 0.f, 0.f};
        if (eg < E) sh4 = *(const f32x4*)(esh + (size_t)eid * 4);
        *(f32x4*)&s_sh[tid * 4] = sh4;     // sh=0 zeroes pad-edge output
    }
    __syncthreads();

    // ---- MLP (MFMA): rbf -> h1 -> h (bf16 rows, stride 72, wave-private) ----
    float cb1[4], cb2[4];
    #pragma unroll
    for (int ct = 0; ct < 4; ++ct) { cb1[ct] = b1[ct*16 + lo]; cb2[ct] = b2[ct*16 + lo]; }
    const short8* W1B = (const short8*)w1b;
    const short8* W2B = (const short8*)w2b;
    const int e0 = 16 * w;

    {
        short8 ar = {0,0,0,0,0,0,0,0};
        if (g < 2 && (eb + e0 + lo) < E) {
            const float* rp = erbf + (size_t)s_eid[e0 + lo] * RBFD + 8 * g;
            f32x4 r0 = *(const f32x4*)rp;
            f32x4 r1 = *(const f32x4*)(rp + 4);
            ar[0]=f2bf(r0[0]); ar[1]=f2bf(r0[1]); ar[2]=f2bf(r0[2]); ar[3]=f2bf(r0[3]);
            ar[4]=f2bf(r1[0]); ar[5]=f2bf(r1[1]); ar[6]=f2bf(r1[2]); ar[7]=f2bf(r1[3]);
        }
        #pragma unroll
        for (int ct = 0; ct < 4; ++ct) {
            f32x4 t = {cb1[ct], cb1[ct], cb1[ct], cb1[ct]};
            t = mfma16(ar, W1B[ct * 64 + l], t);
            #pragma unroll
            for (int r = 0; r < 4; ++r)
                S[(e0 + 4*g + r) * 72 + ct*16 + lo] = f2bf(silu(t[r]));
        }
    }
    {
        short8 h0 = *(const short8*)&S[(e0 + lo) * 72 + 0  + 8*g];
        short8 h1 = *(const short8*)&S[(e0 + lo) * 72 + 32 + 8*g];
        #pragma unroll
        for (int ct = 0; ct < 4; ++ct) {
            f32x4 t = {cb2[ct], cb2[ct], cb2[ct], cb2[ct]};
            t = mfma16(h0, W2B[(ct*2 + 0) * 64 + l], t);
            t = mfma16(h1, W2B[(ct*2 + 1) * 64 + l], t);
            #pragma unroll
            for (int r = 0; r < 4; ++r)
                S[(e0 + 4*g + r) * 72 + ct*16 + lo] = f2bf(silu(t[r]));
        }
    }
    // A-fragments for the main loop (this wave's single row-tile)
    short8 a0 = *(const short8*)&S[(e0 + lo) * 72 + 0  + 8*g];
    short8 a1 = *(const short8*)&S[(e0 + lo) * 72 + 32 + 8*g];
    __syncthreads();   // h rows dead; feature region may overwrite

    // ---- features (bf16) + reordered CPATH-folded b3 staging ----
    if (tid < TE) {
        const int el = tid, grp = el >> 4, e16 = el & 15;
        const float sh0 = s_sh[el*4 + 0];
        const float sh1 = s_sh[el*4 + 1];
        const float sh2 = s_sh[el*4 + 2];
        const float sh3 = s_sh[el*4 + 3];
        const float* xrow = x + (size_t)s_src[el] * FDIM;
        u16* fs4B = S + FS4_U16 + grp * 256 + e16;   // W4 path (C110 * xv.shv)
        u16* xsB  = S + XS_U16  + grp * 512 + e16;   // raw xs (sh_s folded at use)
        u16* xvB  = S + XV_U16  + grp * 768 + e16;   // xv * sh_s
        #pragma unroll
        for (int v = 0; v < 8; ++v) {
            f32x4 x4 = *(const f32x4*)(xrow + 4 * v);
            #pragma unroll
            for (int c2 = 0; c2 < 4; ++c2)
                xsB[(4 * v + c2) * 16] = f2bf(x4[c2]);
        }
        float buf[48];
        #pragma unroll
        for (int v = 0; v < 12; ++v) {
            f32x4 t4 = *(const f32x4*)(xrow + MUL0 + 4 * v);
            buf[4*v]=t4[0]; buf[4*v+1]=t4[1]; buf[4*v+2]=t4[2]; buf[4*v+3]=t4[3];
        }
        #pragma unroll
        for (int i = 0; i < 16; ++i) {
            float v0 = buf[3*i], v1 = buf[3*i+1], v2 = buf[3*i+2];
            xvB[(0  + i) * 16] = f2bf(v0 * sh0);
            xvB[(16 + i) * 16] = f2bf(v1 * sh0);
            xvB[(32 + i) * 16] = f2bf(v2 * sh0);
            fs4B[i * 16]       = f2bf(C110 * (v0*sh1 + v1*sh2 + v2*sh3));
        }
    } else {
        for (int idx = tid - TE; idx < WNUMEL; idx += NTHREADS - TE) {
            int t = idx / 48, r = idx - 48 * t, pair = r >> 4, lo16 = r & 15;
            s_b3[idx] = CPATH * b3[tile_of(t, pair) * 16 + lo16];
        }
    }
    __syncthreads();

    // per-thread sh_s broadcast for the W1-path fold (4 edges per lane-group)
    f32x4 sh0v;
    #pragma unroll
    for (int r = 0; r < 4; ++r)
        sh0v[r] = s_sh[(16*w + 4*g + r) * 4];

    // ---- main loop: DEPTH-3 register pipeline, uniform distance, free-run ----
    const short8* WB = (const short8*)w3n;
    f32x4 acc[6];
    #pragma unroll
    for (int p = 0; p < 6; ++p) acc[p] = (f32x4){0.f,0.f,0.f,0.f};

    short8 p0[6], p1[6], p2[6];
    #pragma unroll
    for (int s = 0; s < 6; ++s) {
        p0[s] = WB[0*384 + s*64 + l];
        p1[s] = WB[1*384 + s*64 + l];
        p2[s] = WB[2*384 + s*64 + l];
    }

    for (int t = 0; t < NITER; t += 3) {
        COMPUTE(t, p0);
        {   const int tn = (t + 3 < NITER) ? (t + 3) : 0;   // wrap: result unused
            #pragma unroll
            for (int s = 0; s < 6; ++s) p0[s] = WB[tn*384 + s*64 + l];
        }
        COMPUTE(t + 1, p1);
        {   const int tn = (t + 4 < NITER) ? (t + 4) : 0;
            #pragma unroll
            for (int s = 0; s < 6; ++s) p1[s] = WB[tn*384 + s*64 + l];
        }
        COMPUTE(t + 2, p2);
        {   const int tn = (t + 5 < NITER) ? (t + 5) : 0;
            #pragma unroll
            for (int s = 0; s < 6; ++s) p2[s] = WB[tn*384 + s*64 + l];
        }
    }

    // ---- epilogue: run-combined atomic scatter (CSR order -> equal dst runs)
    int   dl[4];
    float o0[4], o1[4], o2[4], o3[4], o4[4];
    #pragma unroll
    for (int r = 0; r < 4; ++r) {
        const int e_loc = 16*w + 4*g + r;
        dl[r] = s_dst[e_loc];
        float sv0 = s_sh[e_loc*4 + 1];
        float sv1 = s_sh[e_loc*4 + 2];
        float sv2 = s_sh[e_loc*4 + 3];
        o0[r] = acc[0][r];
        o1[r] = acc[1][r];
        o2[r] = sv0*acc[2][r] + acc[3][r];
        o3[r] = sv1*acc[2][r] + acc[4][r];
        o4[r] = sv2*acc[2][r] + acc[5][r];
    }
    float c0 = 0.f, c1 = 0.f, c2 = 0.f, c3 = 0.f, c4 = 0.f;
    #pragma unroll
    for (int r = 0; r < 4; ++r) {
        c0 += o0[r]; c1 += o1[r]; c2 += o2[r]; c3 += o3[r]; c4 += o4[r];
        bool flush = (r == 3) || (dl[r + 1] != dl[r]);
        if (flush) {
            float* row = agg + (size_t)dl[r] * FDIM;
            atomicAdd(row + lo,      c0);
            atomicAdd(row + 16 + lo, c1);
            atomicAdd(row + MUL0 + lo*3 + 0, c2);
            atomicAdd(row + MUL0 + lo*3 + 1, c3);
            atomicAdd(row + MUL0 + lo*3 + 2, c4);
            c0 = c1 = c2 = c3 = c4 = 0.f;
        }
    }
}

// ---------------------------------------------------------------------------
// Kernel 2: per-node epilogue over atomic agg (= d_out). 16 nodes/block.
// deg from CSR counts (int) -> no deg atomics in k_edge.
// ---------------------------------------------------------------------------
#define NPB 16
__global__ __launch_bounds__(256)
void k_node(const float* __restrict__ x,
            const int*   __restrict__ cnt,
            const float* __restrict__ ws_self,
            const float* __restrict__ wv_self,
            const float* __restrict__ ws_out,
            const float* __restrict__ wv_out,
            float* __restrict__ out)
{
    __shared__ float s_x[NPB][81];
    __shared__ float s_a[NPB][81];
    __shared__ float s_inv[NPB];

    const int tid = threadIdx.x;
    const int n0  = blockIdx.x * NPB;

    if (tid < NPB) s_inv[tid] = 1.0f / fmaxf((float)cnt[n0 + tid], 1.0f);
    const float* xb = x   + (size_t)n0 * FDIM;
    const float* ab = out + (size_t)n0 * FDIM;
    for (int idx = tid; idx < NPB * FDIM; idx += 256) {
        int nl = idx / FDIM, jj = idx - nl * FDIM;
        s_x[nl][jj] = xb[idx];
        s_a[nl][jj] = ab[idx];
    }
    __syncthreads();

    const int j  = tid & 15;
    const int nl = tid >> 4;
    const float inv = s_inv[nl];
    float* orow = out + (size_t)(n0 + nl) * FDIM;

    float s1s = 0.f, s1a = 0.f, s2s = 0.f, s2a = 0.f;
    #pragma unroll
    for (int i = 0; i < MUL0; ++i) {
        float xs = s_x[nl][i], as = s_a[nl][i];
        s1s += xs * ws_self[i * MUL0 + j];
        s1a += as * ws_out [i * MUL0 + j];
        s2s += xs * ws_self[i * MUL0 + j + 16];
        s2a += as * ws_out [i * MUL0 + j + 16];
    }
    orow[j]      = s1s + inv * s1a;
    orow[j + 16] = s2s + inv * s2a;

    float vs[3] = {0.f,0.f,0.f}, va[3] = {0.f,0.f,0.f};
    #pragma unroll
    for (int i = 0; i < MUL1; ++i) {
        float wsf = wv_self[i * MUL1 + j];
        float wof = wv_out [i * MUL1 + j];
        #pragma unroll
        for (int d = 0; d < 3; ++d) {
            vs[d] += s_x[nl][MUL0 + 3*i + d] * wsf;
            va[d] += s_a[nl][MUL0 + 3*i + d] * wof;
        }
    }
    #pragma unroll
    for (int d = 0; d < 3; ++d)
        orow[MUL0 + j*3 + d] = vs[d] + inv * va[d];
}

// ---------------------------------------------------------------------------
extern "C" void kernel_launch(void* const* d_in, const int* in_sizes, int n_in,
                              void* d_out, int out_size, void* d_ws, size_t ws_size,
                              hipStream_t stream)
{
    const float* x       = (const float*)d_in[0];
    const int*   esrc    = (const int*)  d_in[1];
    const int*   edst    = (const int*)  d_in[2];
    const float* esh     = (const float*)d_in[3];
    const float* erbf    = (const float*)d_in[4];
    const float* w1      = (const float*)d_in[5];
    const float* b1      = (const float*)d_in[6];
    const float* w2      = (const float*)d_in[7];
    const float* b2      = (const float*)d_in[8];
    const float* w3      = (const float*)d_in[9];
    const float* b3      = (const float*)d_in[10];
    const float* ws_self = (const float*)d_in[11];
    const float* wv_self = (const float*)d_in[12];
    const float* ws_out  = (const float*)d_in[13];
    const float* wv_out  = (const float*)d_in[14];

    const int N = in_sizes[0] / FDIM;   // 50000
    const int E = in_sizes[1];          // 200000
    const int NB = (N + 255) / 256;     // 196 scan blocks

    // ws layout (256B-aligned chunks)
    char* wsp = (char*)d_ws;
    size_t off = 0;
    auto take = [&](size_t bytes) {
        char* p = wsp + off;
        off += (bytes + 255) & ~(size_t)255;
        return p;
    };
    int* cnt    = (int*)take((size_t)N * 4);
    int* base   = (int*)take((size_t)N * 4);
    int* cursor = (int*)take((size_t)N * 4);
    int* bsum   = (int*)take((size_t)NB * 4);
    int* eidx   = (int*)take((size_t)E * 4);
    u16* w3n    = (u16*)take((size_t)W3N_ELEMS * 2);
    u16* w1b    = (u16*)take((size_t)W1B_ELEMS * 2);
    u16* w2b    = (u16*)take((size_t)W2B_ELEMS * 2);

    hipMemsetAsync(d_out, 0, (size_t)out_size * sizeof(float), stream);
    hipMemsetAsync(cnt, 0, (size_t)N * 4, stream);
    hipMemsetAsync(cursor, 0, (size_t)N * 4, stream);

    k_prep<<<(W3N_ELEMS + W1B_ELEMS + W2B_ELEMS + 255) / 256, 256, 0, stream>>>(
        w3, w1, w2, w3n, w1b, w2b);

    k_cnt      <<<(E + 255) / 256, 256, 0, stream>>>(edst, cnt, E);
    k_scan_part<<<NB, 256, 0, stream>>>(cnt, bsum, N);
    k_scan_top <<<1, 256, 0, stream>>>(bsum, NB);
    k_scan_base<<<NB, 256, 0, stream>>>(cnt, bsum, base, N);
    k_fill     <<<(E + 255) / 256, 256, 0, stream>>>(edst, base, cursor, eidx, E);

    const int nblk = (E + TE - 1) / TE;
    k_edge<<<nblk, NTHREADS, 0, stream>>>(
        x, esrc, edst, esh, erbf, eidx, w1b, b1, w2b, b2, w3n, b3,
        (float*)d_out, E);

    k_node<<<N / NPB, 256, 0, stream>>>(
        x, cnt, ws_self, wv_self, ws_out, wv_out, (float*)d_out);
}